// Round 10
// baseline (6157.080 us; speedup 1.0000x reference)
//
#include <hip/hip_runtime.h>

#define N_NODES 50000
#define NEDGE   800000
#define HID     128

// ---- workspace layout (units: doubles) ----
#define PQ_OFF  32768        // wsd[0..32767] = fp64 W1 rows 0..255 (for pq_kernel)

// ---------------------------------------------------------------------------
// Kernel 0: convert W1 rows 0..255 to fp64 (pq_kernel streams them via s_load).
// ---------------------------------------------------------------------------
__global__ void conv_kernel(const float* __restrict__ w1, double* __restrict__ wsd) {
    const int i = blockIdx.x * 256 + threadIdx.x;
    if (i < 32768) wsd[i] = (double)w1[i];
}

// ---------------------------------------------------------------------------
// Kernel 1: P[n][j] = sum_k f[n][k] w1[k][j] (sel=0), Q with rows 128..255.
// R6-exact form (bit-exact P/Q; ~100 us, not the bottleneck).
// ---------------------------------------------------------------------------
__global__ __launch_bounds__(512, 4)
void pq_kernel(const float* __restrict__ features,
               const double* __restrict__ wsd,
               double* __restrict__ P,
               double* __restrict__ Q) {
    __shared__ float fts[64 * 132];
    const int t  = threadIdx.x;
    const int n0 = blockIdx.x * 64;
    const int sel = blockIdx.y;

    {
        const int n = t & 63, q = t >> 6;
        const int gn = n0 + n;
        #pragma unroll
        for (int i = 0; i < 4; ++i) {
            const int k = q * 16 + i * 4;
            float4 f = make_float4(0.f, 0.f, 0.f, 0.f);
            if (gn < N_NODES) f = *(const float4*)(features + (size_t)gn * HID + k);
            *(float4*)(&fts[n * 132 + k]) = f;
        }
    }
    __syncthreads();

    const int l  = t & 63;
    const int wv = __builtin_amdgcn_readfirstlane(t >> 6);
    const int j0 = wv * 16;
    const double* wb = wsd + (size_t)(sel * 128) * HID + j0;

    double acc[16];
    #pragma unroll
    for (int c = 0; c < 16; ++c) acc[c] = 0.0;

    const float* frow = &fts[l * 132];
    for (int k = 0; k < 128; k += 4) {
        float4 f = *(const float4*)(frow + k);
        #pragma unroll
        for (int kk = 0; kk < 4; ++kk) {
            const double fv = (double)((&f.x)[kk]);
            const double* wr = wb + (size_t)(k + kk) * HID;   // uniform -> s_load
            #pragma unroll
            for (int c = 0; c < 16; ++c)
                acc[c] = fma(fv, wr[c], acc[c]);
        }
    }

    const int gn = n0 + l;
    if (gn < N_NODES) {
        double* dst = (sel ? Q : P) + (size_t)gn * HID + j0;
        #pragma unroll
        for (int c = 0; c < 16; c += 2)
            *(double2*)(dst + c) = make_double2(acc[c], acc[c + 1]);
    }
}

// ---------------------------------------------------------------------------
// Kernel 2 (RESTRUCTURED): block = 256 thr = 4 waves, 64 edges.
//   wave (eh, ch): edges eh*32..+32, cols ch*64 + lane.
// W2 feed: per-lane-distinct coalesced fp32 dword + exact cvt, reused
// across 32 edges (fixes R6-R8 scalar-drain plateau AND R9 L2 hotspot).
// Per-(edge,col) fp64 FMA k-order identical to R6 -> h2 bit-exact; z sum
// is a fixed butterfly tree (fp64 reassoc ~1e-15 << fp32 ulp: safe).
// Epilogue: R6 fp32-granular chain, verbatim.
// ---------------------------------------------------------------------------
__global__ __launch_bounds__(256, 4)
void edge_kernel(const int*   __restrict__ indices,
                 const float* __restrict__ values,
                 const float* __restrict__ tempr,
                 const float* __restrict__ w1,
                 const float* __restrict__ b1,
                 const float* __restrict__ w2,
                 const float* __restrict__ b2,
                 const float* __restrict__ w3,
                 const float* __restrict__ b3,
                 const double* __restrict__ P,
                 const double* __restrict__ Q,
                 float* __restrict__ out) {
    __shared__ double h1s[64 * 65];      // 33.3 KB, h1s[e*65 + (k - kb)]
    __shared__ double zhalf[2][64];      // 1 KB
    const int t  = threadIdx.x;
    const int e0 = blockIdx.x * 64;

    // staging ids
    const int e = t & 63, q = t >> 6;    // q in 0..3 -> 16 k each
    const int ge = e0 + e;
    const int row = indices[ge];
    const int cidx = indices[NEDGE + ge];
    const double v = (double)values[ge];
    const double* prow = P + (size_t)row * HID;
    const double* qrow = Q + (size_t)cidx * HID;

    // compute ids
    const int lane = t & 63;
    const int wv = __builtin_amdgcn_readfirstlane(t >> 6);
    const int eh = wv >> 1;              // edge half (0/1)
    const int ch = wv & 1;               // col half (0/1)
    const int colj = ch * 64 + lane;     // this lane's output column

    double acc[32];
    #pragma unroll
    for (int c = 0; c < 32; ++c) acc[c] = 0.0;

    #pragma unroll
    for (int pass = 0; pass < 2; ++pass) {
        const int kb = pass * 64;

        if (pass) __syncthreads();       // protect h1s reuse

        // ---- stage h1[kb..kb+64) for 64 edges (16 k per thread) ----
        {
            const int kk = kb + q * 16;
            const float* w1c = w1 + (size_t)256 * HID + kk;  // uniform rows
            const float* b1c = b1 + kk;
            double* hdst = &h1s[e * 65 + q * 16];
            #pragma unroll
            for (int i = 0; i < 16; i += 2) {
                double2 pv = *(const double2*)(prow + kk + i);
                double2 qv = *(const double2*)(qrow + kk + i);
                const double wa = (double)w1c[i], wbv = (double)w1c[i + 1];
                const double ba = (double)b1c[i], bb  = (double)b1c[i + 1];
                hdst[i]     = fmax(fma(v, wa,  pv.x + qv.x) + ba, 0.0);
                hdst[i + 1] = fmax(fma(v, wbv, pv.y + qv.y) + bb, 0.0);
            }
        }
        __syncthreads();

        // ---- layer-2 half: lane=col, 32-edge reuse per W2 load ----
        const double* hbase = &h1s[(eh * 32) * 65];
        for (int kp = 0; kp < 64; kp += 2) {
            const int k = kb + kp;
            const float wa32 = w2[(size_t)k * HID + colj];        // coalesced
            const float wb32 = w2[(size_t)(k + 1) * HID + colj];  // coalesced
            const double wda = (double)wa32;                      // exact
            const double wdb = (double)wb32;
            #pragma unroll
            for (int ee = 0; ee < 32; ++ee) {
                double2 h = *(const double2*)(hbase + ee * 65 + kp); // broadcast
                acc[ee] = fma(h.x, wda, acc[ee]);   // k-order same as R6
                acc[ee] = fma(h.y, wdb, acc[ee]);
            }
        }
    }

    // ---- bias+relu, w3 term, butterfly z-reduction over 64 cols ----
    {
        const double b2d = (double)b2[colj];
        const double w3d = (double)w3[colj];
        #pragma unroll
        for (int ee = 0; ee < 32; ++ee) {
            const double h2 = fmax(acc[ee] + b2d, 0.0);
            double term = h2 * w3d;
            #pragma unroll
            for (int d = 1; d < 64; d <<= 1)
                term += __shfl_xor(term, d);        // fixed tree: deterministic
            if (lane == ee) zhalf[ch][eh * 32 + ee] = term;
        }
    }
    __syncthreads();

    // ---- FP32-granular epilogue (R6, bit-exact vs np ref): wave 0 only ----
    if (t < 64) {
        const double z64 = (double)b3[0] + zhalf[0][t] + zhalf[1][t];
        const float z = (float)z64;                 // ref z is fp32

        const float T = tempr[0];
        const int base = t & 48;

        float m = z;
        #pragma unroll
        for (int d = 1; d < 16; d <<= 1) m = fmaxf(m, __shfl_xor(m, d));
        const float e1 = (float)exp((double)(z - m));
        float s = __shfl(e1, base);
        #pragma unroll
        for (int k = 1; k < 16; ++k) s += __shfl(e1, base + k);
        const float pi = e1 / s;

        const float lp = (float)log((double)(pi + 1e-8f));
        const float x  = lp / T;
        const float ex = (float)exp(-(double)x);
        float hard = 1.0f / (1.0f + ex);
        hard = fminf(fmaxf(hard, 0.0f), 1.0f);      // clip (no-op)

        float m2 = hard;
        #pragma unroll
        for (int d = 1; d < 16; d <<= 1) m2 = fmaxf(m2, __shfl_xor(m2, d));
        const float e2 = (float)exp((double)(hard - m2));
        float s2 = __shfl(e2, base);
        #pragma unroll
        for (int k = 1; k < 16; ++k) s2 += __shfl(e2, base + k);
        const float y = e2 / s2;

        int cgt = 0, ceq = 0;
        #pragma unroll
        for (int j = 0; j < 16; ++j) {
            const float yj = __shfl(y, base + j);
            cgt += (yj > y);
            ceq += (yj == y);
        }
        float cand = (cgt <= 7 && cgt + ceq >= 8) ? y : -3.0e38f;
        float thre = cand;
        #pragma unroll
        for (int d = 1; d < 16; d <<= 1) thre = fmaxf(thre, __shfl_xor(thre, d));

        const float g = (y - thre) + 1e-7f;
        out[e0 + t] = (g > 0.0f) ? y : 0.0f;
    }
}

// ---------------------------------------------------------------------------
extern "C" void kernel_launch(void* const* d_in, const int* in_sizes, int n_in,
                              void* d_out, int out_size, void* d_ws, size_t ws_size,
                              hipStream_t stream) {
    const float* features = (const float*)d_in[0];
    const int*   indices  = (const int*)  d_in[1];
    const float* values   = (const float*)d_in[2];
    const float* tempr    = (const float*)d_in[3];
    const float* w1       = (const float*)d_in[4];
    const float* b1       = (const float*)d_in[5];
    const float* w2       = (const float*)d_in[6];
    const float* b2       = (const float*)d_in[7];
    const float* w3       = (const float*)d_in[8];
    const float* b3       = (const float*)d_in[9];
    float* out = (float*)d_out;

    double* wsd = (double*)d_ws;
    double* P = wsd + PQ_OFF;                     // [N][128] fp64
    double* Q = P + (size_t)N_NODES * HID;        // [N][128] fp64

    conv_kernel<<<128, 256, 0, stream>>>(w1, wsd);

    dim3 g1((N_NODES + 63) / 64, 2);
    pq_kernel<<<g1, 512, 0, stream>>>(features, wsd, P, Q);

    dim3 g2(NEDGE / 64);
    edge_kernel<<<g2, 256, 0, stream>>>(indices, values, tempr, w1, b1, w2, b2,
                                        w3, b3, P, Q, out);
}

// Round 11
// 1203.060 us; speedup vs baseline: 5.1178x; 5.1178x over previous
//
#include <hip/hip_runtime.h>

#define N_NODES 50000
#define NEDGE   800000
#define HID     128
#define KS      32           // K-slab per pass

// ---- workspace layout (units: doubles) ----
#define PQ_OFF  32768        // wsd[0..32767] = fp64 W1 rows 0..255 (for pq_kernel)

// ---------------------------------------------------------------------------
// Kernel 0: convert W1 rows 0..255 to fp64 (pq_kernel streams them via s_load).
// ---------------------------------------------------------------------------
__global__ void conv_kernel(const float* __restrict__ w1, double* __restrict__ wsd) {
    const int i = blockIdx.x * 256 + threadIdx.x;
    if (i < 32768) wsd[i] = (double)w1[i];
}

// ---------------------------------------------------------------------------
// Kernel 1: P[n][j] = sum_k f[n][k] w1[k][j] (sel=0), Q with rows 128..255.
// R6-exact form (bit-exact P/Q).
// ---------------------------------------------------------------------------
__global__ __launch_bounds__(512, 4)
void pq_kernel(const float* __restrict__ features,
               const double* __restrict__ wsd,
               double* __restrict__ P,
               double* __restrict__ Q) {
    __shared__ float fts[64 * 132];
    const int t  = threadIdx.x;
    const int n0 = blockIdx.x * 64;
    const int sel = blockIdx.y;

    {
        const int n = t & 63, q = t >> 6;
        const int gn = n0 + n;
        #pragma unroll
        for (int i = 0; i < 4; ++i) {
            const int k = q * 16 + i * 4;
            float4 f = make_float4(0.f, 0.f, 0.f, 0.f);
            if (gn < N_NODES) f = *(const float4*)(features + (size_t)gn * HID + k);
            *(float4*)(&fts[n * 132 + k]) = f;
        }
    }
    __syncthreads();

    const int l  = t & 63;
    const int wv = __builtin_amdgcn_readfirstlane(t >> 6);
    const int j0 = wv * 16;
    const double* wb = wsd + (size_t)(sel * 128) * HID + j0;

    double acc[16];
    #pragma unroll
    for (int c = 0; c < 16; ++c) acc[c] = 0.0;

    const float* frow = &fts[l * 132];
    for (int k = 0; k < 128; k += 4) {
        float4 f = *(const float4*)(frow + k);
        #pragma unroll
        for (int kk = 0; kk < 4; ++kk) {
            const double fv = (double)((&f.x)[kk]);
            const double* wr = wb + (size_t)(k + kk) * HID;   // uniform -> s_load
            #pragma unroll
            for (int c = 0; c < 16; ++c)
                acc[c] = fma(fv, wr[c], acc[c]);
        }
    }

    const int gn = n0 + l;
    if (gn < N_NODES) {
        double* dst = (sel ? Q : P) + (size_t)gn * HID + j0;
        #pragma unroll
        for (int c = 0; c < 16; c += 2)
            *(double2*)(dst + c) = make_double2(acc[c], acc[c + 1]);
    }
}

// ---------------------------------------------------------------------------
// Kernel 2: R6 shape (lane = edge, wave = 16 cols, acc[16]) but W2 fed from
// LDS (fp64, staged in 32-k slabs) via broadcast ds_read_b128 instead of
// s_load. SMEM is unordered -> any s_load use forced lgkmcnt(0) drains that
// serialized every K-step (the 47% VALUBusy plateau, occupancy-invariant);
// LDS returns in-order -> fine-grained lgkmcnt pipelining works.
// h1 stored transposed [k][e]. Per-acc FMA k-order identical to R6.
// fp64 z-order is NOT sacred (R6: absmax 0.0 despite order != np BLAS);
// the fp32 epilogue chain IS sacred and is copied verbatim.
// ---------------------------------------------------------------------------
__global__ __launch_bounds__(512, 4)
void edge_kernel(const int*   __restrict__ indices,
                 const float* __restrict__ values,
                 const float* __restrict__ tempr,
                 const float* __restrict__ w1,
                 const float* __restrict__ b1,
                 const float* __restrict__ w2,
                 const float* __restrict__ b2,
                 const float* __restrict__ w3,
                 const float* __restrict__ b3,
                 const double* __restrict__ P,
                 const double* __restrict__ Q,
                 float* __restrict__ out) {
    __shared__ double w2s[KS * 128];     // 32 KB, [k - kb][j]
    __shared__ double h1s[KS * 64];      // 16 KB, [k - kb][e]  (transposed)
    __shared__ double zpart[8][64];      // 4 KB
    const int t  = threadIdx.x;
    const int e0 = blockIdx.x * 64;

    // staging ids
    const int e = t & 63, q = t >> 6;    // q: 4 ks per pass for this edge
    const int ge = e0 + e;
    const int row  = indices[ge];
    const int cidx = indices[NEDGE + ge];
    const double v = (double)values[ge];
    const double* prow = P + (size_t)row * HID;
    const double* qrow = Q + (size_t)cidx * HID;

    // W2 staging ids: 4096 doubles/pass, 8 per thread
    const int wj = t & 127, wk8 = (t >> 7) * 8;

    // compute ids
    const int l  = t & 63;
    const int wv = __builtin_amdgcn_readfirstlane(t >> 6);
    const int j0 = wv * 16;

    double acc[16];
    #pragma unroll
    for (int c = 0; c < 16; ++c) acc[c] = 0.0;

    #pragma unroll
    for (int pass = 0; pass < 4; ++pass) {
        const int kb = pass * KS;

        if (pass) __syncthreads();       // protect LDS reuse

        // ---- stage W2 slab (fp32 coalesced -> exact cvt -> fp64 LDS) ----
        {
            const float* wsrc = w2 + (size_t)(kb + wk8) * HID + wj;
            #pragma unroll
            for (int i = 0; i < 8; ++i)
                w2s[(wk8 + i) * 128 + wj] = (double)wsrc[(size_t)i * HID];
        }

        // ---- stage h1 slab: thread (e,q) does ks kb+q*4 .. +4 ----
        {
            const int kk = kb + q * 4;
            const float* w1c = w1 + (size_t)256 * HID + kk;   // uniform
            const float* b1c = b1 + kk;                       // uniform
            double2 p0 = *(const double2*)(prow + kk);
            double2 p1 = *(const double2*)(prow + kk + 2);
            double2 q0 = *(const double2*)(qrow + kk);
            double2 q1 = *(const double2*)(qrow + kk + 2);
            const double s0 = p0.x + q0.x, s1 = p0.y + q0.y;
            const double s2 = p1.x + q1.x, s3 = p1.y + q1.y;
            h1s[(q * 4 + 0) * 64 + e] = fmax(fma(v, (double)w1c[0], s0) + (double)b1c[0], 0.0);
            h1s[(q * 4 + 1) * 64 + e] = fmax(fma(v, (double)w1c[1], s1) + (double)b1c[1], 0.0);
            h1s[(q * 4 + 2) * 64 + e] = fmax(fma(v, (double)w1c[2], s2) + (double)b1c[2], 0.0);
            h1s[(q * 4 + 3) * 64 + e] = fmax(fma(v, (double)w1c[3], s3) + (double)b1c[3], 0.0);
        }
        __syncthreads();

        // ---- layer-2 slab: 16 x 2-k iterations ----
        #pragma unroll 4
        for (int kp = 0; kp < KS; kp += 2) {
            const double h0  = h1s[kp * 64 + l];        // lane-distinct b64
            const double h1v = h1s[(kp + 1) * 64 + l];
            const double* wr0 = &w2s[kp * 128 + j0];    // broadcast rows
            const double* wr1 = wr0 + 128;
            #pragma unroll
            for (int c = 0; c < 16; c += 2) {           // same per-acc k-order as R6
                double2 w = *(const double2*)(wr0 + c);
                acc[c]     = fma(h0, w.x, acc[c]);
                acc[c + 1] = fma(h0, w.y, acc[c + 1]);
            }
            #pragma unroll
            for (int c = 0; c < 16; c += 2) {
                double2 w = *(const double2*)(wr1 + c);
                acc[c]     = fma(h1v, w.x, acc[c]);
                acc[c + 1] = fma(h1v, w.y, acc[c + 1]);
            }
        }
    }

    // ---- bias+relu, w3 partial; fixed-order cross-wave reduction ----
    {
        double part = 0.0;
        #pragma unroll
        for (int c = 0; c < 16; ++c) {
            const double h2 = fmax(acc[c] + (double)b2[j0 + c], 0.0);
            part = fma(h2, (double)w3[j0 + c], part);
        }
        zpart[wv][l] = part;
    }
    __syncthreads();

    // ---- FP32-granular epilogue (R6, bit-exact vs np ref): wave 0 only ----
    if (t < 64) {
        double z64 = (double)b3[0];
        #pragma unroll
        for (int w = 0; w < 8; ++w) z64 += zpart[w][t];  // fixed ascending order
        const float z = (float)z64;                      // ref z is fp32

        const float T = tempr[0];
        const int base = t & 48;

        float m = z;
        #pragma unroll
        for (int d = 1; d < 16; d <<= 1) m = fmaxf(m, __shfl_xor(m, d));
        const float e1 = (float)exp((double)(z - m));
        float s = __shfl(e1, base);
        #pragma unroll
        for (int k = 1; k < 16; ++k) s += __shfl(e1, base + k);
        const float pi = e1 / s;

        const float lp = (float)log((double)(pi + 1e-8f));
        const float x  = lp / T;
        const float ex = (float)exp(-(double)x);
        float hard = 1.0f / (1.0f + ex);
        hard = fminf(fmaxf(hard, 0.0f), 1.0f);           // clip (no-op)

        float m2 = hard;
        #pragma unroll
        for (int d = 1; d < 16; d <<= 1) m2 = fmaxf(m2, __shfl_xor(m2, d));
        const float e2 = (float)exp((double)(hard - m2));
        float s2 = __shfl(e2, base);
        #pragma unroll
        for (int k = 1; k < 16; ++k) s2 += __shfl(e2, base + k);
        const float y = e2 / s2;

        int cgt = 0, ceq = 0;
        #pragma unroll
        for (int j = 0; j < 16; ++j) {
            const float yj = __shfl(y, base + j);
            cgt += (yj > y);
            ceq += (yj == y);
        }
        float cand = (cgt <= 7 && cgt + ceq >= 8) ? y : -3.0e38f;
        float thre = cand;
        #pragma unroll
        for (int d = 1; d < 16; d <<= 1) thre = fmaxf(thre, __shfl_xor(thre, d));

        const float g = (y - thre) + 1e-7f;
        out[e0 + t] = (g > 0.0f) ? y : 0.0f;
    }
}

// ---------------------------------------------------------------------------
extern "C" void kernel_launch(void* const* d_in, const int* in_sizes, int n_in,
                              void* d_out, int out_size, void* d_ws, size_t ws_size,
                              hipStream_t stream) {
    const float* features = (const float*)d_in[0];
    const int*   indices  = (const int*)  d_in[1];
    const float* values   = (const float*)d_in[2];
    const float* tempr    = (const float*)d_in[3];
    const float* w1       = (const float*)d_in[4];
    const float* b1       = (const float*)d_in[5];
    const float* w2       = (const float*)d_in[6];
    const float* b2       = (const float*)d_in[7];
    const float* w3       = (const float*)d_in[8];
    const float* b3       = (const float*)d_in[9];
    float* out = (float*)d_out;

    double* wsd = (double*)d_ws;
    double* P = wsd + PQ_OFF;                     // [N][128] fp64
    double* Q = P + (size_t)N_NODES * HID;        // [N][128] fp64

    conv_kernel<<<128, 256, 0, stream>>>(w1, wsd);

    dim3 g1((N_NODES + 63) / 64, 2);
    pq_kernel<<<g1, 512, 0, stream>>>(features, wsd, P, Q);

    dim3 g2(NEDGE / 64);
    edge_kernel<<<g2, 512, 0, stream>>>(indices, values, tempr, w1, b1, w2, b2,
                                        w3, b3, P, Q, out);
}